// Round 1
// baseline (2222.880 us; speedup 1.0000x reference)
//
#include <hip/hip_runtime.h>
#include <math.h>

#define C_DIM 512
#define HW    196
#define E_DIM 64
#define TOPK  8

// One block per batch row b. 256 threads = 4 waves.
// Phase 1: pool [C,H,W] -> pooled[C] (fp64 accum, fp32 loads).
// Phase 2: wave 0 computes routing logits, softmaxes, top-8.
__global__ __launch_bounds__(256)
void noisy_topk_router_kernel(const float* __restrict__ mh,
                              const float* __restrict__ noise,
                              const float* __restrict__ Wr,
                              const float* __restrict__ br,
                              const float* __restrict__ Wn,
                              const float* __restrict__ bn,
                              float* __restrict__ out_router, // [B,8]
                              float* __restrict__ out_idx,    // [B,8] (as float)
                              float* __restrict__ out_noisy)  // [B,64]
{
    const int b    = blockIdx.x;
    const int tid  = threadIdx.x;
    const int lane = tid & 63;
    const int wave = tid >> 6;

    __shared__ double pooled[C_DIM];

    // ---------- Phase 1: global average pool ----------
    // Each row (b,c) is 196 floats = 49 float4, 16B-aligned (784B stride).
    const float* base = mh + (size_t)b * (C_DIM * HW);
    for (int c = wave; c < C_DIM; c += 4) {
        double s = 0.0;
        if (lane < 49) {
            const float4 v =
                *reinterpret_cast<const float4*>(base + c * HW + lane * 4);
            s = ((double)v.x + (double)v.y) + ((double)v.z + (double)v.w);
        }
        #pragma unroll
        for (int off = 32; off >= 1; off >>= 1)
            s += __shfl_down(s, off, 64);
        if (lane == 0) pooled[c] = s * (1.0 / 196.0);
    }
    __syncthreads();
    if (wave != 0) return;

    // ---------- Phase 2: routing (wave 0, lane = expert e) ----------
    const int e = lane;
    double ar = (double)br[e];
    double an = (double)bn[e];
    const float* wr = Wr + e * C_DIM;
    const float* wn = Wn + e * C_DIM;
    #pragma unroll 8
    for (int c = 0; c < C_DIM; ++c) {
        const double p = pooled[c];          // LDS broadcast (same addr)
        ar += p * (double)wr[c];
        an += p * (double)wn[c];
    }

    // softmax over route logits (butterfly: every lane gets max/sum)
    double m = ar;
    #pragma unroll
    for (int off = 32; off >= 1; off >>= 1)
        m = fmax(m, __shfl_xor(m, off, 64));
    const double ex = exp(ar - m);
    double s = ex;
    #pragma unroll
    for (int off = 32; off >= 1; off >>= 1)
        s += __shfl_xor(s, off, 64);
    const double logit_sm = ex / s;

    // noise branch: softmax(noise * softplus(noise_logits))
    const double sp = fmax(an, 0.0) + log1p(exp(-fabs(an)));
    const double z  = (double)noise[b * E_DIM + e] * sp;
    double m2 = z;
    #pragma unroll
    for (int off = 32; off >= 1; off >>= 1)
        m2 = fmax(m2, __shfl_xor(m2, off, 64));
    const double e2 = exp(z - m2);
    double s2 = e2;
    #pragma unroll
    for (int off = 32; off >= 1; off >>= 1)
        s2 += __shfl_xor(s2, off, 64);
    const double noise_sm = e2 / s2;

    const double noisy = logit_sm + noise_sm;
    out_noisy[b * E_DIM + e] = (float)noisy;

    // ---------- top-8 (descending value, ties -> lower index) ----------
    double v = noisy;
    const int idx = e;
    double tv[TOPK];
    int    ti[TOPK];
    #pragma unroll
    for (int k = 0; k < TOPK; ++k) {
        double bv = v;
        int    bi = idx;
        #pragma unroll
        for (int off = 32; off >= 1; off >>= 1) {
            const double ov = __shfl_xor(bv, off, 64);
            const int    oi = __shfl_xor(bi, off, 64);
            if (ov > bv || (ov == bv && oi < bi)) { bv = ov; bi = oi; }
        }
        tv[k] = bv;
        ti[k] = bi;
        if (idx == bi) v = -(double)INFINITY;  // winner zaps itself
    }

    // softmax over the 8 selected (tv[0] is the max)
    const double mx = tv[0];
    double ssum = 0.0;
    #pragma unroll
    for (int i = 0; i < TOPK; ++i) ssum += exp(tv[i] - mx);
    const double inv = 1.0 / ssum;
    #pragma unroll
    for (int i = 0; i < TOPK; ++i) {
        if (lane == i) {
            out_router[b * TOPK + i] = (float)(exp(tv[i] - mx) * inv);
            out_idx[b * TOPK + i]    = (float)ti[i];
        }
    }
}

extern "C" void kernel_launch(void* const* d_in, const int* in_sizes, int n_in,
                              void* d_out, int out_size, void* d_ws, size_t ws_size,
                              hipStream_t stream) {
    const float* mh    = (const float*)d_in[0];
    const float* noise = (const float*)d_in[1];
    const float* Wr    = (const float*)d_in[2];
    const float* br    = (const float*)d_in[3];
    const float* Wn    = (const float*)d_in[4];
    const float* bn    = (const float*)d_in[5];

    const int B = in_sizes[1] / E_DIM;  // 4096

    float* out        = (float*)d_out;
    float* out_router = out;                 // B*8
    float* out_idx    = out + (size_t)B * TOPK;       // B*8
    float* out_noisy  = out + (size_t)B * TOPK * 2;   // B*64

    noisy_topk_router_kernel<<<B, 256, 0, stream>>>(
        mh, noise, Wr, br, Wn, bn, out_router, out_idx, out_noisy);
}